// Round 7
// baseline (625.335 us; speedup 1.0000x reference)
//
#include <hip/hip_runtime.h>
#include <hip/hip_bf16.h>
#include <math.h>

typedef unsigned short u16;
typedef unsigned int   u32;

typedef __bf16 bf16x8 __attribute__((ext_vector_type(8)));
typedef float  f32x4  __attribute__((ext_vector_type(4)));
#define MFMA_B16 __builtin_amdgcn_mfma_f32_16x16x32_bf16

// Native RNE converts (compiler emits v_cvt_*_bf16).
__device__ __forceinline__ u16 f2b(float f) {
    union { __bf16 h; u16 u; } v; v.h = (__bf16)f; return v.u;
}
__device__ __forceinline__ u32 pk2(float a, float b) {
    union { __bf16 h[2]; u32 u; } v;
    v.h[0] = (__bf16)a; v.h[1] = (__bf16)b; return v.u;
}
__device__ __forceinline__ bf16x8 pk8(float4 f0, float4 f1) {
    bf16x8 r;
    r[0] = (__bf16)f0.x; r[1] = (__bf16)f0.y; r[2] = (__bf16)f0.z; r[3] = (__bf16)f0.w;
    r[4] = (__bf16)f1.x; r[5] = (__bf16)f1.y; r[6] = (__bf16)f1.z; r[7] = (__bf16)f1.w;
    return r;
}

// Fast GELU (tanh form) = v * sigmoid(1.5957691 v + 0.07135486 v^3)
__device__ __forceinline__ float gelu_fast(float v) {
    const float z = v * (1.5957691f + 0.07135486f * v * v);
    return v * __builtin_amdgcn_rcpf(1.0f + __expf(-z));
}

// LDS index swizzles (keep ds_read_b128 16B blocks intact; spread banks).
__device__ __forceinline__ int qk_idx(int row, int d) {
    return row * 32 + (d ^ (((row >> 1) & 3) << 3));
}
__device__ __forceinline__ int p_idx(int row, int col) {
    return row * 64 + (col ^ ((row & 7) << 3));
}

#define SCALE_ 0.17677669529663687f   // 32^-0.5
#define EPS_   1e-3f

// ---------------- workspace layout (bytes) ----------------
// 0       : wqkvT  bf16 [384][128]   (98304 B)
// 98304   : wprojT bf16 [128][128]   (32768 B)
// 131072  : w1T    bf16 [512][128]   (131072 B)
// 262144  : w2T    bf16 [128][512]   (131072 B)
// 393216  : rpbm   fp32 [4][4][64][64] (262144 B)   rpb + shift-mask folded
// total 655360 B

__global__ __launch_bounds__(256) void swin_prep(
    const float* __restrict__ w_qkv, const float* __restrict__ w_proj,
    const float* __restrict__ w_fc1, const float* __restrict__ w_fc2,
    const float* __restrict__ bias_table, const int* __restrict__ rel_index,
    const float* __restrict__ attn_mask,
    u16* __restrict__ wqkvT, u16* __restrict__ wprojT,
    u16* __restrict__ w1T, u16* __restrict__ w2T, float* __restrict__ rpbm)
{
    const int idx = blockIdx.x * 256 + threadIdx.x;
    if (idx < 49152) {                       // qkv: [o<384][c<128]
        const int o = idx >> 7, c = idx & 127;
        wqkvT[idx] = f2b(w_qkv[c * 384 + o]);
    } else if (idx < 65536) {                // proj: [o<128][c<128]
        const int i2 = idx - 49152;
        const int o = i2 >> 7, c = i2 & 127;
        wprojT[i2] = f2b(w_proj[c * 128 + o]);
    } else if (idx < 131072) {               // fc1: [o<512][c<128]
        const int i2 = idx - 65536;
        const int o = i2 >> 7, c = i2 & 127;
        w1T[i2] = f2b(w_fc1[c * 512 + o]);
    } else if (idx < 196608) {               // fc2: [o<128][u<512]
        const int i2 = idx - 131072;
        const int o = i2 >> 9, u = i2 & 511;
        w2T[i2] = f2b(w_fc2[u * 128 + o]);
    } else if (idx < 262144) {               // rpbm[cls][h][i][j]
        const int i2 = idx - 196608;
        const int cls = i2 >> 14, rem = i2 & 16383;
        const int h = rem >> 12, ij = rem & 4095;
        const int widx = ((cls & 2) ? 240 : 0) + ((cls & 1) ? 15 : 0);
        rpbm[i2] = bias_table[rel_index[ij] * 4 + h] + attn_mask[widx * 4096 + ij];
    }
}

// =====================================================================
// Kernel A: shifted-window attention (MFMA) + proj + LN1 + residual -> x1
// One block per window; wave w == head w. Phases 1-3 are WAVE-LOCAL:
// wave w computes exactly head w's q/k/v (col remap), q/k stored
// head-interleaved so P[h] overlays only its own head's q+k. No barrier
// until the cross-head AO/proj phases. Barriers: 3 (B3a, B3b, B4).
// LDS (u16 idx, sm[25600] = 51200 B -> 3 blocks/CU):
//  qk [h][ q 64x32 swz | k 64x32 swz ] @ h*4096   (16384 total)
//  vT [4][32][72]         @ 16384  (9216)
//  P  [h][ 64x64 swz ]    @ h*4096 (overlays own q+k, wave-local)
//  AO bf16 [64][136]      @ 0      (8704, overlays P[0..1], after B3a)
//  X2 fp32 [64][132]      @ f-idx 4352 (u16 [8704,25600), overlays P-tail+vT)
// =====================================================================
#define VA_OFF  16384
#define AO_OFF  0
#define X2F_OFF 4352   // float idx (byte 17408)

__global__ __launch_bounds__(256, 3) void swin_attn_mfma(
    const float* __restrict__ x, const u16* __restrict__ wqkvT, const float* __restrict__ b_qkv,
    const u16* __restrict__ wprojT, const float* __restrict__ b_proj,
    const float* __restrict__ g1, const float* __restrict__ be1,
    const float* __restrict__ rpbm, float* __restrict__ x1out)
{
    __shared__ __align__(16) u16 sm[25600];
    const int tid  = threadIdx.x;
    const int w    = tid >> 6;          // wave / head
    const int lane = tid & 63;
    const int l15  = lane & 15;
    const int quad = lane >> 4;
    const int win  = blockIdx.x;
    const int b = win >> 8, wr = (win >> 4) & 15, wc = win & 15;

    // token-row global bases for A-fragment rows t = mi*16 + l15
    size_t rowb[4];
    #pragma unroll
    for (int mi = 0; mi < 4; mi++) {
        const int t  = mi * 16 + l15;
        const int hh = (wr * 8 + (t >> 3) + 4) & 127;
        const int ww = (wc * 8 + (t & 7) + 4) & 127;
        rowb[mi] = ((size_t)((b * 128 + hh) * 128 + ww)) * 128;
    }

    // ---- Phase 1: QKV GEMM, wave w computes HEAD w's q/k/v only ----
    // o(n) = (n>>1)*128 + w*32 + (n&1)*16 + l15  (s = n>>1: 0=q,1=k,2=v)
    {
        f32x4 acc[6][4];
        #pragma unroll
        for (int n = 0; n < 6; n++) {
            const float bq = b_qkv[(n >> 1) * 128 + w * 32 + (n & 1) * 16 + l15];
            #pragma unroll
            for (int mi = 0; mi < 4; mi++) acc[n][mi] = (f32x4){bq, bq, bq, bq};
        }
        #pragma unroll
        for (int ks = 0; ks < 4; ks++) {
            bf16x8 a[4], bb[6];
            #pragma unroll
            for (int mi = 0; mi < 4; mi++) {
                const float4 f0 = *(const float4*)(x + rowb[mi] + ks * 32 + quad * 8);
                const float4 f1 = *(const float4*)(x + rowb[mi] + ks * 32 + quad * 8 + 4);
                a[mi] = pk8(f0, f1);
            }
            #pragma unroll
            for (int n = 0; n < 6; n++)
                bb[n] = *(const bf16x8*)(wqkvT
                    + (size_t)((n >> 1) * 128 + w * 32 + (n & 1) * 16 + l15) * 128 + ks * 32 + quad * 8);
            #pragma unroll
            for (int n = 0; n < 6; n++)
                #pragma unroll
                for (int mi = 0; mi < 4; mi++)
                    acc[n][mi] = MFMA_B16(a[mi], bb[n], acc[n][mi], 0, 0, 0);
        }
        // scatter: q/k head-interleaved (wave-local), vT per head
        #pragma unroll
        for (int n = 0; n < 6; n++) {
            const int s = n >> 1, d = (n & 1) * 16 + l15;
            #pragma unroll
            for (int mi = 0; mi < 4; mi++) {
                if (s < 2) {
                    const int base = w * 4096 + s * 2048;
                    const float sc = s ? 1.0f : SCALE_;
                    #pragma unroll
                    for (int r = 0; r < 4; r++) {
                        const int row = mi * 16 + quad * 4 + r;
                        sm[base + qk_idx(row, d)] = f2b(acc[n][mi][r] * sc);
                    }
                } else {
                    const int t0 = mi * 16 + quad * 4;
                    const u32 w0 = pk2(acc[n][mi][0], acc[n][mi][1]);
                    const u32 w1 = pk2(acc[n][mi][2], acc[n][mi][3]);
                    *(uint2*)(sm + VA_OFF + w * 2304 + d * 72 + t0) = make_uint2(w0, w1);
                }
            }
        }
    }
    // NO barrier: q/k/vT for head w are written and read only by wave w.

    // ---- Phase 2: scores (MFMA) + softmax (registers), wave-local ----
    float sinv[4][4];
    {
        const float* rb = rpbm + (size_t)((((wr == 15) ? 2 : 0) | ((wc == 15) ? 1 : 0)) * 4 + w) * 4096;
        f32x4 S[4][4];
        #pragma unroll
        for (int mi = 0; mi < 4; mi++)
            #pragma unroll
            for (int ni = 0; ni < 4; ni++)
                #pragma unroll
                for (int r = 0; r < 4; r++)
                    S[mi][ni][r] = rb[(mi * 16 + quad * 4 + r) * 64 + ni * 16 + l15];
        bf16x8 aq[4], bk[4];
        #pragma unroll
        for (int mi = 0; mi < 4; mi++)
            aq[mi] = *(const bf16x8*)(sm + w * 4096 + qk_idx(mi * 16 + l15, quad * 8));
        #pragma unroll
        for (int ni = 0; ni < 4; ni++)
            bk[ni] = *(const bf16x8*)(sm + w * 4096 + 2048 + qk_idx(ni * 16 + l15, quad * 8));
        #pragma unroll
        for (int mi = 0; mi < 4; mi++)
            #pragma unroll
            for (int ni = 0; ni < 4; ni++)
                S[mi][ni] = MFMA_B16(aq[mi], bk[ni], S[mi][ni], 0, 0, 0);
        #pragma unroll
        for (int mi = 0; mi < 4; mi++) {
            #pragma unroll
            for (int r = 0; r < 4; r++) {
                float m0 = fmaxf(fmaxf(S[mi][0][r], S[mi][1][r]), fmaxf(S[mi][2][r], S[mi][3][r]));
                m0 = fmaxf(m0, __shfl_xor(m0, 1));
                m0 = fmaxf(m0, __shfl_xor(m0, 2));
                m0 = fmaxf(m0, __shfl_xor(m0, 4));
                m0 = fmaxf(m0, __shfl_xor(m0, 8));
                float s0 = 0.0f;
                #pragma unroll
                for (int ni = 0; ni < 4; ni++) {
                    const float e = __expf(S[mi][ni][r] - m0);
                    S[mi][ni][r] = e;
                    s0 += e;
                }
                s0 += __shfl_xor(s0, 1);
                s0 += __shfl_xor(s0, 2);
                s0 += __shfl_xor(s0, 4);
                s0 += __shfl_xor(s0, 8);
                sinv[mi][r] = __builtin_amdgcn_rcpf(s0);
            }
        }
        // NO barrier: P[w] overlays exactly this wave's own q+k region;
        // in-wave DS ordering (lgkmcnt, in-order per wave) protects RAW.

        // ---- Phase 3: P -> LDS (swizzled, own region), PV (MFMA) ----
        #pragma unroll
        for (int mi = 0; mi < 4; mi++)
            #pragma unroll
            for (int ni = 0; ni < 4; ni++)
                #pragma unroll
                for (int r = 0; r < 4; r++)
                    sm[w * 4096 + p_idx(mi * 16 + quad * 4 + r, ni * 16 + l15)] = f2b(S[mi][ni][r]);

        f32x4 O[4][2];
        #pragma unroll
        for (int mi = 0; mi < 4; mi++)
            #pragma unroll
            for (int ni = 0; ni < 2; ni++) O[mi][ni] = (f32x4){0.f, 0.f, 0.f, 0.f};
        #pragma unroll
        for (int ks = 0; ks < 2; ks++) {
            bf16x8 ap[4], bv[2];
            #pragma unroll
            for (int mi = 0; mi < 4; mi++)
                ap[mi] = *(const bf16x8*)(sm + w * 4096 + p_idx(mi * 16 + l15, ks * 32 + quad * 8));
            #pragma unroll
            for (int ni = 0; ni < 2; ni++)
                bv[ni] = *(const bf16x8*)(sm + VA_OFF + w * 2304 + (ni * 16 + l15) * 72 + ks * 32 + quad * 8);
            #pragma unroll
            for (int mi = 0; mi < 4; mi++)
                #pragma unroll
                for (int ni = 0; ni < 2; ni++)
                    O[mi][ni] = MFMA_B16(ap[mi], bv[ni], O[mi][ni], 0, 0, 0);
        }
        __syncthreads();   // B3a: ALL waves' PV done; AO may overlay P[0..2]

        #pragma unroll
        for (int mi = 0; mi < 4; mi++)
            #pragma unroll
            for (int ni = 0; ni < 2; ni++)
                #pragma unroll
                for (int r = 0; r < 4; r++)
                    sm[AO_OFF + (mi * 16 + quad * 4 + r) * 136 + w * 32 + ni * 16 + l15]
                        = f2b(O[mi][ni][r] * sinv[mi][r]);
    }
    __syncthreads();   // B3b: AO complete (cross-head proj reads all cols)

    // ---- Phase 4: prefetch residual x (for phase 5), proj -> X2 LDS ----
    float4 xres[8];
    size_t gout;
    {
        const int t = tid >> 2, part = tid & 3;
        const int hh = (wr * 8 + (t >> 3) + 4) & 127;
        const int ww = (wc * 8 + (t & 7) + 4) & 127;
        gout = ((size_t)((b * 128 + hh) * 128 + ww)) * 128 + part * 32;
        #pragma unroll
        for (int k = 0; k < 8; k++)
            xres[k] = *(const float4*)(x + gout + k * 4);   // hides under proj MFMAs
    }
    {
        f32x4 X2[4][2];
        #pragma unroll
        for (int ni = 0; ni < 2; ni++) {
            const float bp = b_proj[w * 32 + ni * 16 + l15];
            #pragma unroll
            for (int mi = 0; mi < 4; mi++) X2[mi][ni] = (f32x4){bp, bp, bp, bp};
        }
        #pragma unroll
        for (int ks = 0; ks < 4; ks++) {
            bf16x8 aa[4], bw[2];
            #pragma unroll
            for (int mi = 0; mi < 4; mi++)
                aa[mi] = *(const bf16x8*)(sm + AO_OFF + (mi * 16 + l15) * 136 + ks * 32 + quad * 8);
            #pragma unroll
            for (int ni = 0; ni < 2; ni++)
                bw[ni] = *(const bf16x8*)(wprojT + (size_t)(w * 32 + ni * 16 + l15) * 128 + ks * 32 + quad * 8);
            #pragma unroll
            for (int mi = 0; mi < 4; mi++)
                #pragma unroll
                for (int ni = 0; ni < 2; ni++)
                    X2[mi][ni] = MFMA_B16(aa[mi], bw[ni], X2[mi][ni], 0, 0, 0);
        }
        float* X2f = (float*)sm + X2F_OFF;
        #pragma unroll
        for (int mi = 0; mi < 4; mi++)
            #pragma unroll
            for (int ni = 0; ni < 2; ni++)
                #pragma unroll
                for (int r = 0; r < 4; r++)
                    X2f[(mi * 16 + quad * 4 + r) * 132 + w * 32 + ni * 16 + l15] = X2[mi][ni][r];
    }
    __syncthreads();   // B4: X2f complete

    // ---- Phase 5: LN1 + residual (4 threads per token row) ----
    {
        const int t = tid >> 2, part = tid & 3;
        const float* Xr = (const float*)sm + X2F_OFF + t * 132 + part * 32;
        float4 xr[8];
        float s1 = 0.f, s2 = 0.f;
        #pragma unroll
        for (int k = 0; k < 8; k++) {
            xr[k] = *(const float4*)(Xr + k * 4);
            s1 += xr[k].x + xr[k].y + xr[k].z + xr[k].w;
            s2 += xr[k].x * xr[k].x + xr[k].y * xr[k].y
                + xr[k].z * xr[k].z + xr[k].w * xr[k].w;
        }
        s1 += __shfl_xor(s1, 1); s1 += __shfl_xor(s1, 2);
        s2 += __shfl_xor(s2, 1); s2 += __shfl_xor(s2, 2);
        const float m  = s1 * 0.0078125f;
        const float vr = fmaxf(s2 * 0.0078125f - m * m, 0.f);
        const float rs = rsqrtf(vr + EPS_);
        #pragma unroll
        for (int k = 0; k < 8; k++) {
            const int c4 = k * 4;
            const float4 gv = *(const float4*)(g1 + part * 32 + c4);
            const float4 bv = *(const float4*)(be1 + part * 32 + c4);
            float4 o;
            o.x = xres[k].x + (xr[k].x - m) * rs * gv.x + bv.x;
            o.y = xres[k].y + (xr[k].y - m) * rs * gv.y + bv.y;
            o.z = xres[k].z + (xr[k].z - m) * rs * gv.z + bv.z;
            o.w = xres[k].w + (xr[k].w - m) * rs * gv.w + bv.w;
            *(float4*)(x1out + gout + c4) = o;
        }
    }
}

// =====================================================================
// Kernel B: MLP (fc1 -> GELU -> fc2 in 4 chunks of 128 hidden, DOUBLE-
// BUFFERED h) + LN2 + residual, in-place on x1. (unchanged from R6)
// LDS (u16 idx, sm[26112] = 52224 B -> 3 blocks/CU):
//  xt bf16 [64][136] @ 0                  (8704)
//  h0 bf16 [64][136] @ 8704, h1 @ 17408   (8704 each)
//  X3 fp32 [64][132] @ f-idx 4352 (overlays h0+h1 after final barrier)
// =====================================================================
#define HB0_OFF 8704
#define X3F_OFF 4352   // float idx (byte 17408)

__global__ __launch_bounds__(256, 3) void swin_mlp_mfma(
    float* __restrict__ x1io, const u16* __restrict__ w1T, const float* __restrict__ b_fc1,
    const u16* __restrict__ w2T, const float* __restrict__ b_fc2,
    const float* __restrict__ g2, const float* __restrict__ be2)
{
    __shared__ __align__(16) u16 sm[26112];
    const int tid  = threadIdx.x;
    const int w    = tid >> 6;
    const int lane = tid & 63;
    const int l15  = lane & 15;
    const int quad = lane >> 4;
    const size_t base = (size_t)blockIdx.x * 8192;

    for (int e = tid * 8; e < 8192; e += 2048) {
        const int t = e >> 7, c = e & 127;
        const float4 f0 = *(const float4*)(x1io + base + e);
        const float4 f1 = *(const float4*)(x1io + base + e + 4);
        union { bf16x8 v; uint4 u; } cv; cv.v = pk8(f0, f1);
        *(uint4*)(sm + t * 136 + c) = cv.u;
    }
    __syncthreads();   // xt ready

    f32x4 acc2[2][4];   // [ni][mi] fc2 accumulator, persists across chunks
    #pragma unroll
    for (int ni = 0; ni < 2; ni++) {
        const float bb = b_fc2[w * 32 + ni * 16 + l15];
        #pragma unroll
        for (int mi = 0; mi < 4; mi++) acc2[ni][mi] = (f32x4){bb, bb, bb, bb};
    }

    for (int ch = 0; ch < 4; ch++) {
        u16* hb = sm + HB0_OFF + (ch & 1) * 8704;
        // fc1 chunk (128 hidden cols) + GELU -> h[ch&1]
        f32x4 a1[2][4];   // [ni][mi]
        #pragma unroll
        for (int ni = 0; ni < 2; ni++) {
            const float bb = b_fc1[ch * 128 + (w * 2 + ni) * 16 + l15];
            #pragma unroll
            for (int mi = 0; mi < 4; mi++) a1[ni][mi] = (f32x4){bb, bb, bb, bb};
        }
        #pragma unroll
        for (int ks = 0; ks < 4; ks++) {
            bf16x8 af[4], bf[2];
            #pragma unroll
            for (int mi = 0; mi < 4; mi++)
                af[mi] = *(const bf16x8*)(sm + (mi * 16 + l15) * 136 + ks * 32 + quad * 8);
            #pragma unroll
            for (int ni = 0; ni < 2; ni++)
                bf[ni] = *(const bf16x8*)(w1T + (size_t)(ch * 128 + (w * 2 + ni) * 16 + l15) * 128 + ks * 32 + quad * 8);
            #pragma unroll
            for (int ni = 0; ni < 2; ni++)
                #pragma unroll
                for (int mi = 0; mi < 4; mi++)
                    a1[ni][mi] = MFMA_B16(af[mi], bf[ni], a1[ni][mi], 0, 0, 0);
        }
        #pragma unroll
        for (int ni = 0; ni < 2; ni++)
            #pragma unroll
            for (int mi = 0; mi < 4; mi++)
                #pragma unroll
                for (int r = 0; r < 4; r++) {
                    const float v = gelu_fast(a1[ni][mi][r]);
                    hb[(mi * 16 + quad * 4 + r) * 136 + (w * 2 + ni) * 16 + l15] = f2b(v);
                }
        __syncthreads();   // B(ch): h[ch&1] ready (and fc2(ch-1) globally done)
        // fc2 partial accumulate over this chunk
        #pragma unroll
        for (int ks = 0; ks < 4; ks++) {
            bf16x8 ah[4], bh[2];
            #pragma unroll
            for (int mi = 0; mi < 4; mi++)
                ah[mi] = *(const bf16x8*)(hb + (mi * 16 + l15) * 136 + ks * 32 + quad * 8);
            #pragma unroll
            for (int ni = 0; ni < 2; ni++)
                bh[ni] = *(const bf16x8*)(w2T + (size_t)(w * 32 + ni * 16 + l15) * 512 + ch * 128 + ks * 32 + quad * 8);
            #pragma unroll
            for (int ni = 0; ni < 2; ni++)
                #pragma unroll
                for (int mi = 0; mi < 4; mi++)
                    acc2[ni][mi] = MFMA_B16(ah[mi], bh[ni], acc2[ni][mi], 0, 0, 0);
        }
        // no trailing barrier: next chunk writes the OTHER h buffer
    }
    __syncthreads();   // all fc2 reads done; X3 may overlay h0/h1

    // X3 fp32 into h region
    {
        float* X3 = (float*)sm + X3F_OFF;
        #pragma unroll
        for (int ni = 0; ni < 2; ni++)
            #pragma unroll
            for (int mi = 0; mi < 4; mi++)
                #pragma unroll
                for (int r = 0; r < 4; r++)
                    X3[(mi * 16 + quad * 4 + r) * 132 + w * 32 + ni * 16 + l15] = acc2[ni][mi][r];
    }
    __syncthreads();

    // LN2 + residual (4 threads per token row), write back in place.
    {
        const int t = tid >> 2, part = tid & 3;
        const float* Xr = (const float*)sm + X3F_OFF + t * 132 + part * 32;
        float4 xr[8];
        float s1 = 0.f, s2 = 0.f;
        #pragma unroll
        for (int k = 0; k < 8; k++) {
            xr[k] = *(const float4*)(Xr + k * 4);
            s1 += xr[k].x + xr[k].y + xr[k].z + xr[k].w;
            s2 += xr[k].x * xr[k].x + xr[k].y * xr[k].y
                + xr[k].z * xr[k].z + xr[k].w * xr[k].w;
        }
        s1 += __shfl_xor(s1, 1); s1 += __shfl_xor(s1, 2);
        s2 += __shfl_xor(s2, 1); s2 += __shfl_xor(s2, 2);
        const float m  = s1 * 0.0078125f;
        const float vr = fmaxf(s2 * 0.0078125f - m * m, 0.f);
        const float rs = rsqrtf(vr + EPS_);
        const size_t g = base + t * 128 + part * 32;
        #pragma unroll
        for (int k = 0; k < 8; k++) {
            const int c4 = k * 4;
            const float4 xv = *(const float4*)(x1io + g + c4);
            const float4 gv = *(const float4*)(g2 + part * 32 + c4);
            const float4 bv = *(const float4*)(be2 + part * 32 + c4);
            float4 o;
            o.x = xv.x + (xr[k].x - m) * rs * gv.x + bv.x;
            o.y = xv.y + (xr[k].y - m) * rs * gv.y + bv.y;
            o.z = xv.z + (xr[k].z - m) * rs * gv.z + bv.z;
            o.w = xv.w + (xr[k].w - m) * rs * gv.w + bv.w;
            *(float4*)(x1io + g + c4) = o;
        }
    }
}

extern "C" void kernel_launch(void* const* d_in, const int* in_sizes, int n_in,
                              void* d_out, int out_size, void* d_ws, size_t ws_size,
                              hipStream_t stream) {
    const float* x         = (const float*)d_in[0];
    const float* w_qkv     = (const float*)d_in[1];
    const float* b_qkv     = (const float*)d_in[2];
    const float* bias_tab  = (const float*)d_in[3];
    const float* w_proj    = (const float*)d_in[4];
    const float* b_proj    = (const float*)d_in[5];
    const float* g1        = (const float*)d_in[6];
    const float* be1       = (const float*)d_in[7];
    const float* w_fc1     = (const float*)d_in[8];
    const float* b_fc1     = (const float*)d_in[9];
    const float* w_fc2     = (const float*)d_in[10];
    const float* b_fc2     = (const float*)d_in[11];
    const float* g2        = (const float*)d_in[12];
    const float* be2       = (const float*)d_in[13];
    const int* rel_index   = (const int*)d_in[14];
    const float* attn_mask = (const float*)d_in[15];

    char* ws = (char*)d_ws;
    u16*   wqkvT  = (u16*)ws;
    u16*   wprojT = (u16*)(ws + 98304);
    u16*   w1T    = (u16*)(ws + 131072);
    u16*   w2T    = (u16*)(ws + 262144);
    float* rpbm   = (float*)(ws + 393216);

    float* x1 = (float*)d_out;   // x1 lives in d_out; kernel B is in-place

    swin_prep<<<1024, 256, 0, stream>>>(w_qkv, w_proj, w_fc1, w_fc2,
                                        bias_tab, rel_index, attn_mask,
                                        wqkvT, wprojT, w1T, w2T, rpbm);
    swin_attn_mfma<<<4096, 256, 0, stream>>>(x, wqkvT, b_qkv, wprojT, b_proj,
                                             g1, be1, rpbm, x1);
    swin_mlp_mfma<<<4096, 256, 0, stream>>>(x1, w1T, b_fc1, w2T, b_fc2, g2, be2);
}